// Round 11
// baseline (218.676 us; speedup 1.0000x reference)
//
#include <hip/hip_runtime.h>
#include <hip/hip_bf16.h>
#include <math.h>

#define D_MODEL 1024
#define NHEAD   16
#define HDIM    64
#define BATCH   2
#define SEQ     2048
#define MTOT    (BATCH * SEQ)  // 4096

typedef unsigned short u16;
typedef unsigned int u32;
typedef short short8 __attribute__((ext_vector_type(8)));
typedef float floatx4 __attribute__((ext_vector_type(4)));

#define LOG2E 1.44269504088896340736f

#if __has_builtin(__builtin_amdgcn_exp2f)
#define EXP2(x) __builtin_amdgcn_exp2f(x)
#else
#define EXP2(x) exp2f(x)
#endif

static __device__ __forceinline__ u16 f2b(float f) {
  union { __hip_bfloat16 h; u16 u; } cv;
  cv.h = __float2bfloat16(f);
  return cv.u;
}

// async global->LDS, 16 bytes per lane; LDS dest must be wave-uniform base +
// lane*16 (our staging layouts satisfy this by construction).
typedef const __attribute__((address_space(1))) unsigned int guint;
typedef __attribute__((address_space(3))) unsigned int luint;
static __device__ __forceinline__ void gl_lds16(const u16* g, u16* l) {
  __builtin_amdgcn_global_load_lds((guint*)g, (luint*)l, 16, 0, 0);
}

// ---------------------------------------------------------------------------
// fused fp32 -> bf16 cast of x (4Mi), w_qkv (3Mi), w_proj (1Mi): one launch.
// ---------------------------------------------------------------------------
__global__ __launch_bounds__(256) void cast3_f2b(
    const float* __restrict__ a, u16* __restrict__ ao, int na,
    const float* __restrict__ b, u16* __restrict__ bo, int nb,
    const float* __restrict__ c, u16* __restrict__ co) {
  int i = (blockIdx.x * 256 + threadIdx.x) * 4;
  const float* src;
  u16* dst;
  if (i < na) {
    src = a + i;
    dst = ao + i;
  } else if (i < na + nb) {
    src = b + (i - na);
    dst = bo + (i - na);
  } else {
    src = c + (i - na - nb);
    dst = co + (i - na - nb);
  }
  float4 v = *(const float4*)src;
  ushort4 o;
  o.x = f2b(v.x);
  o.y = f2b(v.y);
  o.z = f2b(v.z);
  o.w = f2b(v.w);
  *(ushort4*)dst = o;
}

// ---------------------------------------------------------------------------
// bf16 NT MFMA GEMM (QKV): C[m,n] = dot(A[m,:], B[n,:]) + bias[n]
// 128 x 128 tile, BK=32, 256 threads = 4 waves.
// Double-buffered LDS, gl_lds width-16 staging (prefetch after barrier).
// Q/K -> [B,H,T,HD] via LDS-coalesced epilogue; V -> [B,H,HD,T] transposed.
// ---------------------------------------------------------------------------
__global__ __launch_bounds__(256) void gemm_qkv(
    const u16* __restrict__ A, const u16* __restrict__ Bm,
    const float* __restrict__ bias, u16* __restrict__ Cq, u16* __restrict__ Ck,
    u16* __restrict__ Cvt, int M, int N, int K) {
  __shared__ u16 smem[17408];  // staging 2x(128+128)x32 = 32KB; epi 34.8KB
  u16(*As)[128][32] = (u16(*)[128][32])smem;
  u16(*Bs)[128][32] = (u16(*)[128][32])(smem + 8192);

  const int tid = threadIdx.x;
  const int lane = tid & 63;
  const int wave = tid >> 6;
  const int wm = (wave >> 1) * 64;
  const int wn = (wave & 1) * 64;
  const int quad = lane >> 4;
  const int l15 = lane & 15;
  const int m0 = blockIdx.y * 128;
  const int n0 = blockIdx.x * 128;

  const int srow = wave * 16 + (lane >> 2);
  const int k8 = (lane & 3) * 8;

  const u16* gA0 = A + (size_t)(m0 + srow) * K + k8;
  const u16* gA1 = A + (size_t)(m0 + srow + 64) * K + k8;
  const u16* gB0 = Bm + (size_t)(n0 + srow) * K + k8;
  const u16* gB1 = Bm + (size_t)(n0 + srow + 64) * K + k8;

  floatx4 acc[4][4];
#pragma unroll
  for (int i = 0; i < 4; ++i)
#pragma unroll
    for (int j = 0; j < 4; ++j)
#pragma unroll
      for (int e = 0; e < 4; ++e) acc[i][j][e] = 0.0f;

  gl_lds16(gA0, &As[0][srow][k8]);
  gl_lds16(gA1, &As[0][srow + 64][k8]);
  gl_lds16(gB0, &Bs[0][srow][k8]);
  gl_lds16(gB1, &Bs[0][srow + 64][k8]);

  const int niter = K / 32;
  for (int kt = 0; kt < niter; ++kt) {
    const int cur = kt & 1;
    __syncthreads();
    if (kt + 1 < niter) {
      const int k0n = (kt + 1) * 32;
      gl_lds16(gA0 + k0n, &As[cur ^ 1][srow][k8]);
      gl_lds16(gA1 + k0n, &As[cur ^ 1][srow + 64][k8]);
      gl_lds16(gB0 + k0n, &Bs[cur ^ 1][srow][k8]);
      gl_lds16(gB1 + k0n, &Bs[cur ^ 1][srow + 64][k8]);
    }
    short8 af[4], bf[4];
#pragma unroll
    for (int i = 0; i < 4; ++i)
      af[i] = *(const short8*)&As[cur][wm + i * 16 + l15][quad * 8];
#pragma unroll
    for (int j = 0; j < 4; ++j)
      bf[j] = *(const short8*)&Bs[cur][wn + j * 16 + l15][quad * 8];
#pragma unroll
    for (int i = 0; i < 4; ++i)
#pragma unroll
      for (int j = 0; j < 4; ++j)
        acc[i][j] = __builtin_amdgcn_mfma_f32_16x16x32_bf16(af[i], bf[j],
                                                            acc[i][j], 0, 0, 0);
  }

  // epilogue. C frag elem r: row = wm+i*16+quad*4+r, col = wn+j*16+l15
  const int nbase = n0 + wn;
  const int sel = nbase >> 10;
  const int h = (nbase >> 6) & (NHEAD - 1);
  if (sel == 2) {
    // V transposed: [B,H,HD,T]; 4 consecutive t pack into one store
#pragma unroll
    for (int j = 0; j < 4; ++j) {
      const int n = nbase + j * 16 + l15;
      const float bv = bias[n];
      const int d = n & (HDIM - 1);
#pragma unroll
      for (int i = 0; i < 4; ++i) {
        const int mb = m0 + wm + i * 16 + quad * 4;
        const int b = mb >> 11;
        const int t = mb & (SEQ - 1);
        ushort4 o4;
        o4.x = f2b(acc[i][j][0] + bv);
        o4.y = f2b(acc[i][j][1] + bv);
        o4.z = f2b(acc[i][j][2] + bv);
        o4.w = f2b(acc[i][j][3] + bv);
        *(ushort4*)(Cvt + ((size_t)(b * NHEAD + h) * HDIM + d) * SEQ + t) = o4;
      }
    }
  } else {
    u16* dst = (sel == 0) ? Cq : Ck;
    __syncthreads();  // staging LDS reads done; repurpose as scratch
    u16(*Ct)[68] = (u16(*)[68])(smem + wave * 4352);  // 64 rows x 68
#pragma unroll
    for (int j = 0; j < 4; ++j) {
      const float bv = bias[nbase + j * 16 + l15];
#pragma unroll
      for (int i = 0; i < 4; ++i)
#pragma unroll
        for (int r = 0; r < 4; ++r)
          Ct[i * 16 + quad * 4 + r][j * 16 + l15] = f2b(acc[i][j][r] + bv);
    }
    const int mb0 = m0 + wm;
    const int b = mb0 >> 11;
    const int t0 = mb0 & (SEQ - 1);
    u16* rowbase = dst + ((size_t)(b * NHEAD + h) * SEQ + t0) * HDIM;
    const int tr = lane >> 3;
    const int d8 = (lane & 7) * 8;
#pragma unroll
    for (int p = 0; p < 8; ++p) {
      const int row = p * 8 + tr;
      *(short8*)(rowbase + (size_t)row * HDIM + d8) =
          *(const short8*)&Ct[row][d8];
    }
  }
}

// ---------------------------------------------------------------------------
// Output-projection GEMM: 64 x 128 tile, BK=64 (16 iters -> half the
// barrier/drain count of BK=32), fp32 row-major out.
// ---------------------------------------------------------------------------
__global__ __launch_bounds__(256) void gemm_proj_k64(
    const u16* __restrict__ A, const u16* __restrict__ Bm,
    const float* __restrict__ bias, float* __restrict__ Cf, int M, int N,
    int K) {
  __shared__ u16 As[2][64][64];   // 16 KB
  __shared__ u16 Bs[2][128][64];  // 32 KB

  const int tid = threadIdx.x;
  const int lane = tid & 63;
  const int wave = tid >> 6;
  const int wm = (wave >> 1) * 32;
  const int wn = (wave & 1) * 64;
  const int quad = lane >> 4;
  const int l15 = lane & 15;
  const int m0 = blockIdx.y * 64;
  const int n0 = blockIdx.x * 128;

  // staging: row = wave*8 + (lane>>3), k8 = (lane&7)*8
  // LDS addr = base + lane*16B (row stride 128 B) -> gl_lds-compatible
  const int srow = wave * 8 + (lane >> 3);  // 0..31
  const int k8 = (lane & 7) * 8;

  const u16* gA0 = A + (size_t)(m0 + srow) * K + k8;
  const u16* gA1 = A + (size_t)(m0 + srow + 32) * K + k8;
  const u16* gB0 = Bm + (size_t)(n0 + srow) * K + k8;
  const u16* gB1 = Bm + (size_t)(n0 + srow + 32) * K + k8;
  const u16* gB2 = Bm + (size_t)(n0 + srow + 64) * K + k8;
  const u16* gB3 = Bm + (size_t)(n0 + srow + 96) * K + k8;

  floatx4 acc[2][4];
#pragma unroll
  for (int i = 0; i < 2; ++i)
#pragma unroll
    for (int j = 0; j < 4; ++j)
#pragma unroll
      for (int e = 0; e < 4; ++e) acc[i][j][e] = 0.0f;

  gl_lds16(gA0, &As[0][srow][k8]);
  gl_lds16(gA1, &As[0][srow + 32][k8]);
  gl_lds16(gB0, &Bs[0][srow][k8]);
  gl_lds16(gB1, &Bs[0][srow + 32][k8]);
  gl_lds16(gB2, &Bs[0][srow + 64][k8]);
  gl_lds16(gB3, &Bs[0][srow + 96][k8]);

  const int niter = K / 64;  // 16
  for (int kt = 0; kt < niter; ++kt) {
    const int cur = kt & 1;
    __syncthreads();
    if (kt + 1 < niter) {
      const int k0n = (kt + 1) * 64;
      gl_lds16(gA0 + k0n, &As[cur ^ 1][srow][k8]);
      gl_lds16(gA1 + k0n, &As[cur ^ 1][srow + 32][k8]);
      gl_lds16(gB0 + k0n, &Bs[cur ^ 1][srow][k8]);
      gl_lds16(gB1 + k0n, &Bs[cur ^ 1][srow + 32][k8]);
      gl_lds16(gB2 + k0n, &Bs[cur ^ 1][srow + 64][k8]);
      gl_lds16(gB3 + k0n, &Bs[cur ^ 1][srow + 96][k8]);
    }
    short8 af[2][2], bf[4][2];
#pragma unroll
    for (int i = 0; i < 2; ++i)
#pragma unroll
      for (int kk = 0; kk < 2; ++kk)
        af[i][kk] =
            *(const short8*)&As[cur][wm + i * 16 + l15][kk * 32 + quad * 8];
#pragma unroll
    for (int j = 0; j < 4; ++j)
#pragma unroll
      for (int kk = 0; kk < 2; ++kk)
        bf[j][kk] =
            *(const short8*)&Bs[cur][wn + j * 16 + l15][kk * 32 + quad * 8];
#pragma unroll
    for (int i = 0; i < 2; ++i)
#pragma unroll
      for (int j = 0; j < 4; ++j) {
        acc[i][j] = __builtin_amdgcn_mfma_f32_16x16x32_bf16(
            af[i][0], bf[j][0], acc[i][j], 0, 0, 0);
        acc[i][j] = __builtin_amdgcn_mfma_f32_16x16x32_bf16(
            af[i][1], bf[j][1], acc[i][j], 0, 0, 0);
      }
  }

#pragma unroll
  for (int j = 0; j < 4; ++j) {
    const int n = n0 + wn + j * 16 + l15;
    const float bv = bias[n];
#pragma unroll
    for (int i = 0; i < 2; ++i) {
      const int mb = m0 + wm + i * 16 + quad * 4;
#pragma unroll
      for (int r = 0; r < 4; ++r)
        Cf[(size_t)(mb + r) * N + n] = acc[i][j][r] + bv;
    }
  }
}

// ---------------------------------------------------------------------------
// MFMA flash attention v6: ONE 64-row q-tile per block, 1024 blocks,
// heavy-first (qt = 31-bx) -> LPT backfill scheduling; 3 blocks/CU (48.6 KB).
// 256 threads = 4 waves; wave owns 16 rows. Double-buffered K/V, ONE barrier
// per k-iter; Q A-frags direct from global; un-normalized exp2; row-sum l via
// MFMA against a CONSTANT register ones-B-frag (l15==0 ? 1.0 : 0).
// Q/K bf16 [B,H,T,HD]; V bf16 TRANSPOSED [B,H,HD,T]; Y bf16 [B,T,D].
// ---------------------------------------------------------------------------
__global__ __launch_bounds__(256) void flash_mfma(const u16* __restrict__ Qg,
                                                  const u16* __restrict__ Kg,
                                                  const u16* __restrict__ Vtg,
                                                  u16* __restrict__ Yb) {
  __shared__ u16 Ks[2][64][76];  // [buf][kc][d]   19456 B
  __shared__ u16 Vt[2][64][76];  // [buf][d][kc]   19456 B
  __shared__ u16 Pb[64][76];     // [row][kc]       9728 B

  const int tid = threadIdx.x;
  const int lane = tid & 63;
  const int wave = tid >> 6;  // 0..3
  const int wrow = wave * 16;
  const int quad = lane >> 4;
  const int l15 = lane & 15;
  const int bh = blockIdx.y;
  const int b = bh >> 4;
  const int h = bh & (NHEAD - 1);

  const u16* Qp = Qg + (size_t)bh * SEQ * HDIM;
  const u16* Kp = Kg + (size_t)bh * SEQ * HDIM;
  const u16* Vp = Vtg + (size_t)bh * HDIM * SEQ;

  const int srow = tid >> 2;      // 0..63
  const int sc = (tid & 3) * 16;  // 0,16,32,48 (two 8-chunks: sc, sc+8)

  const float scale2 = 0.125f * LOG2E;

  const int qt = 31 - blockIdx.x;  // heavy tiles dispatch first (LPT)
  const int q0 = qt * 64;

  // constant ones B-frag for the l-accumulation MFMA: B[n=l15][k]=1 iff n==0
  short8 onesf;
  {
    const short ov = (l15 == 0) ? (short)0x3F80 : (short)0;
#pragma unroll
    for (int e = 0; e < 8; ++e) onesf[e] = ov;
  }

  // Q A-frags direct from global, persistent across the k-loop
  short8 aq[2];
  {
    const u16* qrow = Qp + (size_t)(q0 + wrow + l15) * HDIM + quad * 8;
    aq[0] = *(const short8*)qrow;
    aq[1] = *(const short8*)(qrow + 32);
  }

  floatx4 o[5];  // o[0..3]: output dims; o[4] col l15==0 = row-sum l
#pragma unroll
  for (int c = 0; c < 5; ++c)
#pragma unroll
    for (int e = 0; e < 4; ++e) o[c][e] = 0.0f;

  const int nkt = qt + 1;
  // preload first K/V tile into regs
  short8 kv0 = *(const short8*)(Kp + (size_t)srow * HDIM + sc);
  short8 kv1 = *(const short8*)(Kp + (size_t)srow * HDIM + sc + 8);
  short8 vv0 = *(const short8*)(Vp + (size_t)srow * SEQ + sc);
  short8 vv1 = *(const short8*)(Vp + (size_t)srow * SEQ + sc + 8);

  for (int kt = 0; kt < nkt; ++kt) {
    const int k0 = kt * 64;
    const int buf = kt & 1;
    *(short8*)&Ks[buf][srow][sc] = kv0;
    *(short8*)&Ks[buf][srow][sc + 8] = kv1;
    *(short8*)&Vt[buf][srow][sc] = vv0;
    *(short8*)&Vt[buf][srow][sc + 8] = vv1;
    __syncthreads();  // ONE barrier per iteration (dbuf spacing argument)
    if (kt + 1 < nkt) {  // prefetch next tile; in flight during compute
      const u16* kp = Kp + (size_t)(k0 + 64 + srow) * HDIM + sc;
      const u16* vp = Vp + (size_t)srow * SEQ + k0 + 64 + sc;
      kv0 = *(const short8*)kp;
      kv1 = *(const short8*)(kp + 8);
      vv0 = *(const short8*)vp;
      vv1 = *(const short8*)(vp + 8);
    }

    // ---- S = Q K^T ----
    short8 bk[4][2];
#pragma unroll
    for (int c = 0; c < 4; ++c)
#pragma unroll
      for (int kk = 0; kk < 2; ++kk)
        bk[c][kk] = *(const short8*)&Ks[buf][c * 16 + l15][kk * 32 + quad * 8];

    floatx4 s[4];
#pragma unroll
    for (int c = 0; c < 4; ++c) {
#pragma unroll
      for (int e = 0; e < 4; ++e) s[c][e] = 0.0f;
      s[c] = __builtin_amdgcn_mfma_f32_16x16x32_bf16(aq[0], bk[c][0], s[c], 0,
                                                     0, 0);
      s[c] = __builtin_amdgcn_mfma_f32_16x16x32_bf16(aq[1], bk[c][1], s[c], 0,
                                                     0, 0);
    }

    // ---- scale + mask (diagonal tile only) + exp2 -> P ----
    const bool msk = (kt == nkt - 1);
    const int prow = wrow + quad * 4;
#pragma unroll
    for (int c = 0; c < 4; ++c)
#pragma unroll
      for (int r = 0; r < 4; ++r) {
        float v = s[c][r] * scale2;
        if (msk) {
          const int row = q0 + prow + r;
          const int col = k0 + c * 16 + l15;
          if (col > row) v = -INFINITY;
        }
        Pb[prow + r][c * 16 + l15] = f2b(EXP2(v));
      }

    // ---- O_aug += P [V | 1] (P rows wave-local; per-wave LDS order) ----
    short8 ap[2];
#pragma unroll
    for (int kk = 0; kk < 2; ++kk)
      ap[kk] = *(const short8*)&Pb[wrow + l15][kk * 32 + quad * 8];
#pragma unroll
    for (int c = 0; c < 4; ++c) {
      short8 bv0 = *(const short8*)&Vt[buf][c * 16 + l15][quad * 8];
      short8 bv1 = *(const short8*)&Vt[buf][c * 16 + l15][32 + quad * 8];
      o[c] = __builtin_amdgcn_mfma_f32_16x16x32_bf16(ap[0], bv0, o[c], 0, 0,
                                                     0);
      o[c] = __builtin_amdgcn_mfma_f32_16x16x32_bf16(ap[1], bv1, o[c], 0, 0,
                                                     0);
    }
    o[4] = __builtin_amdgcn_mfma_f32_16x16x32_bf16(ap[0], onesf, o[4], 0, 0,
                                                   0);
    o[4] = __builtin_amdgcn_mfma_f32_16x16x32_bf16(ap[1], onesf, o[4], 0, 0,
                                                   0);
  }

  // ---- epilogue: l lives in o[4] lanes with l15==0; broadcast in-quad ----
#pragma unroll
  for (int r = 0; r < 4; ++r) {
    const float lr = __shfl(o[4][r], lane & 48);
    const float inv = 1.0f / lr;
    const int t = q0 + wrow + quad * 4 + r;
#pragma unroll
    for (int c = 0; c < 4; ++c)
      Yb[((size_t)b * SEQ + t) * D_MODEL + h * HDIM + c * 16 + l15] =
          f2b(o[c][r] * inv);
  }
}

// ---------------------------------------------------------------------------
extern "C" void kernel_launch(void* const* d_in, const int* in_sizes, int n_in,
                              void* d_out, int out_size, void* d_ws,
                              size_t ws_size, hipStream_t stream) {
  const float* x = (const float*)d_in[0];
  // d_in[1] = attn_mask (bool tril) — statically causal, ignored.
  const float* w_qkv = (const float*)d_in[2];
  const float* b_qkv = (const float*)d_in[3];
  const float* w_proj = (const float*)d_in[4];
  const float* b_proj = (const float*)d_in[5];
  float* out = (float*)d_out;

  const size_t nx = (size_t)MTOT * D_MODEL;          // 4 Mi
  const size_t nwq = (size_t)3 * D_MODEL * D_MODEL;  // 3 Mi
  const size_t nwp = (size_t)D_MODEL * D_MODEL;      // 1 Mi
  const size_t nqkv = (size_t)BATCH * NHEAD * SEQ * HDIM;  // 4 Mi

  u16* xb = (u16*)d_ws;
  u16* wqb = xb + nx;
  u16* wpb = wqb + nwq;
  u16* qb = wpb + nwp;
  u16* kb = qb + nqkv;
  u16* vtb = kb + nqkv;  // [B,H,HD,T]
  u16* yb = vtb + nqkv;  // 48 MB total

  cast3_f2b<<<dim3((nx + nwq + nwp) / 1024), dim3(256), 0, stream>>>(
      x, xb, (int)nx, w_qkv, wqb, (int)nwq, w_proj, wpb);

  // QKV projection: M=4096, N=3072, K=1024
  gemm_qkv<<<dim3(24, 32), dim3(256), 0, stream>>>(
      xb, wqb, b_qkv, qb, kb, vtb, MTOT, 3 * D_MODEL, D_MODEL);
  // flash attention: 32 q-tiles (heavy-first) x 32 (b,h) = 1024 blocks
  flash_mfma<<<dim3(32, BATCH * NHEAD), dim3(256), 0, stream>>>(qb, kb, vtb,
                                                                yb);
  // output projection: M=4096, N=1024, K=1024 (fp32 out), BK=64
  gemm_proj_k64<<<dim3(8, 64), dim3(256), 0, stream>>>(
      yb, wpb, b_proj, out, MTOT, D_MODEL, D_MODEL);
}